// Round 10
// baseline (103.519 us; speedup 1.0000x reference)
//
#include <hip/hip_runtime.h>
#include <hip/hip_bf16.h>
#include <float.h>

// Problem constants
#define BATCH 8
#define CHN   64
#define HW    56
#define PIX   3136          // 56*56
#define LDB   72            // band LDS stride in bf16 elems (144 B, 16-B aligned)
#define DSTR  16            // dots row stride (doubles): slots 0..14 used
#define JW    28            // pixels per fused block (half row)
#define BCOLS 32            // band cols per fused block (JW + 2*2 halo)

typedef __bf16 bf16x8 __attribute__((ext_vector_type(8)));
typedef float  f32x4  __attribute__((ext_vector_type(4)));

static __device__ __forceinline__ unsigned short f2bf(float f) {
    unsigned int u = __float_as_uint(f);
    u += 0x7fffu + ((u >> 16) & 1u);          // round-to-nearest-even
    return (unsigned short)(u >> 16);
}

// ---------------------------------------------------------------------------
// Stage 1: dots[b][p][s], s=0..14 (window rows dr<=0), fp64 sequential over
// c=0..63 — bit-identical to the R1-verified keys. Rows dr=+1,+2 are exact
// mirrors (IEEE mul commutes): read as dots[q][24-s] in stage 2.
// Thread = (b, r, s, j). s==12 also emits invn. Tail blocks pack wbf.
// [R9-verified]
// ---------------------------------------------------------------------------
__global__ __launch_bounds__(256) void dots_kernel(const float* __restrict__ x,
                                                   const float* __restrict__ w,
                                                   double* __restrict__ dots,
                                                   double* __restrict__ invn,
                                                   unsigned short* __restrict__ wbf) {
    int idx = blockIdx.x * 256 + threadIdx.x;
    if (idx >= 376320) {                          // 16 tail blocks: pack wbf
        int wi = idx - 376320;                    // 4096 threads x 9 elems
        #pragma unroll
        for (int k = 0; k < 9; k++) {
            int l = wi + k * 4096;                // l = (o*9+tap)*64 + c
            int otap = l >> 6, c = l & 63;
            int o = otap / 9, tap = otap - o * 9;
            wbf[l] = f2bf(w[(o * CHN + c) * 9 + tap]);
        }
        return;
    }
    const int b  = idx / 47040;
    int rem      = idx - b * 47040;
    const int r  = rem / 840;
    rem          = rem - r * 840;
    const int s  = rem / 56;                      // 0..14
    const int j  = rem - s * 56;
    const int p  = r * HW + j;
    const int dr = s / 5 - 2, dc = s % 5 - 2;
    const int qi = r + dr, qj = j + dc;
    int q = qi * HW + qj;
    q = q < 0 ? 0 : (q >= PIX ? PIX - 1 : q);     // clamp (invalid -> masked later)

    const float* xp = x + (size_t)b * CHN * PIX + p;
    const float* xq = x + (size_t)b * CHN * PIX + q;
    double acc = 0.0;
    #pragma unroll 8
    for (int c = 0; c < CHN; c++) {
        acc += (double)xp[c * PIX] * (double)xq[c * PIX];
    }
    dots[((size_t)b * PIX + p) * DSTR + s] = acc;
    if (s == 12) invn[(size_t)b * PIX + p] = 1.0 / sqrt(acc);
}

// ---------------------------------------------------------------------------
// Stage 2 (fused select + gather-conv), per (b, row r, half). 28 pixels per
// block -> 896 blocks (2x R9 occupancy; band 23 KB + qtab -> 6 blocks/CU).
// Lanes t<28: build 25 keys from global dots (s<15 direct, s>=15 mirror
// dots[q][24-s]) * invn[q], DBL_MAX invalid — bit-identical to verified
// selection; 9-rank stable select + ascending index sort -> qtab.
// t in [28,32): zero qtab tails. t>=64: stage bf16 band (rows r-2..r+2,
// cols jbase-2..jbase+29, zero-padded). Then indexed-ds_read_b128 MFMA
// (9 taps x 2 n-tiles x 2 k-halves per wave), direct out write.
// ---------------------------------------------------------------------------
__global__ __launch_bounds__(256) void fused_kernel(const float* __restrict__ x,
                                                    const double* __restrict__ dots,
                                                    const double* __restrict__ invn,
                                                    const unsigned short* __restrict__ wbf,
                                                    float* __restrict__ out) {
    const int half = blockIdx.x;
    const int r = blockIdx.y;
    const int b = blockIdx.z;
    const int jbase = half * JW;
    __shared__ unsigned short band[5 * BCOLS * LDB];   // 23040 B
    __shared__ int qtab[9 * 32];                       // 1152 B
    const int t = threadIdx.x;

    // A-fragments (registers; b128 loads from packed wbf)
    const int wv = t >> 6, ln = t & 63;
    const int mrow = ln & 15, kq = ln >> 4;
    const int o = wv * 16 + mrow;
    bf16x8 afr[9][2];
    #pragma unroll
    for (int tap = 0; tap < 9; tap++) {
        #pragma unroll
        for (int hf = 0; hf < 2; hf++) {
            afr[tap][hf] = *(const bf16x8*)(wbf + (size_t)(o * 9 + tap) * 64 + hf * 32 + kq * 8);
        }
    }

    if (t < JW) {
        const int jj = jbase + t;
        const double* dp  = dots + ((size_t)b * PIX + r * HW + jj) * DSTR;
        const double* inb = invn + (size_t)b * PIX;
        double k2[25];
        #pragma unroll
        for (int s = 0; s < 25; s++) {
            int dr = s / 5 - 2, dc = s % 5 - 2;
            int qi = r + dr, qj = jj + dc;
            bool valid = qi >= 0 && qi < HW && qj >= 0 && qj < HW;
            int q = qi * HW + qj;
            double raw;
            if (s < 15) raw = dp[s];
            else        raw = valid ? dots[((size_t)b * PIX + q) * DSTR + (24 - s)] : 0.0;
            k2[s] = valid ? raw * inb[q] : DBL_MAX;
        }
        unsigned int used = 0;
        int bq[9];
        #pragma unroll
        for (int rr = 0; rr < 9; rr++) {
            double best = DBL_MAX; int bs = 0;
            #pragma unroll
            for (int s = 0; s < 25; s++) {
                bool ok = (((used >> s) & 1u) == 0u) && (k2[s] < best);
                if (ok) { best = k2[s]; bs = s; }
            }
            used |= (1u << bs);
            bq[rr] = (r + bs / 5 - 2) * HW + (jj + bs % 5 - 2);
        }
        #pragma unroll
        for (int a = 0; a < 8; a++) {
            #pragma unroll
            for (int c2 = 0; c2 < 8 - a; c2++) {
                int u = bq[c2], v = bq[c2 + 1];
                bq[c2] = u < v ? u : v; bq[c2 + 1] = u < v ? v : u;
            }
        }
        #pragma unroll
        for (int k = 0; k < 9; k++) {
            int q = bq[k], qi = q / HW, qj = q - qi * HW;
            qtab[k * 32 + t] = ((qi - r + 2) * BCOLS + (qj - jbase + 2)) * LDB;
        }
    } else if (t < 32) {
        #pragma unroll
        for (int k = 0; k < 9; k++) qtab[k * 32 + t] = 0;   // tail dummy
    } else if (t >= 64) {
        // band: 160 locals x 32 channel-pairs; lanes sweep locals (coalesced)
        const float* xb = x + (size_t)b * CHN * PIX;
        for (int l = t - 64; l < 5120; l += 192) {
            int cpair = l / 160;
            int local = l - cpair * 160;
            int lr = local >> 5, lc = local & 31;
            int row = r - 2 + lr;
            int col = jbase + lc - 2;
            unsigned int pk = 0;
            if (row >= 0 && row < HW && col >= 0 && col < HW) {
                int q = row * HW + col;
                float v0 = xb[(size_t)(2 * cpair) * PIX + q];
                float v1 = xb[(size_t)(2 * cpair + 1) * PIX + q];
                pk = (unsigned int)f2bf(v0) | ((unsigned int)f2bf(v1) << 16);
            }
            *(unsigned int*)&band[local * LDB + 2 * cpair] = pk;
        }
    }
    __syncthreads();

    // MFMA gather-conv (verified structure; 2 n-tiles)
    f32x4 oacc[2] = {{0,0,0,0},{0,0,0,0}};
    #pragma unroll
    for (int tap = 0; tap < 9; tap++) {
        #pragma unroll
        for (int nt = 0; nt < 2; nt++) {
            int q = qtab[tap * 32 + nt * 16 + mrow];
            const unsigned short* bp = &band[q + kq * 8];
            bf16x8 b0 = *(const bf16x8*)bp;
            bf16x8 b1 = *(const bf16x8*)(bp + 32);
            oacc[nt] = __builtin_amdgcn_mfma_f32_16x16x32_bf16(afr[tap][0], b0, oacc[nt], 0, 0, 0);
            oacc[nt] = __builtin_amdgcn_mfma_f32_16x16x32_bf16(afr[tap][1], b1, oacc[nt], 0, 0, 0);
        }
    }
    // C/D: col = lane&15 = p-within-tile, row = kq*4+rg = o-within-strip
    float* ob = out + ((size_t)b * 64 + wv * 16 + kq * 4) * PIX + r * HW + jbase;
    #pragma unroll
    for (int nt = 0; nt < 2; nt++) {
        int p = nt * 16 + mrow;
        if (p < JW) {
            #pragma unroll
            for (int rg = 0; rg < 4; rg++) ob[(size_t)rg * PIX + p] = oacc[nt][rg];
        }
    }
}

// ---------------------------------------------------------------------------
// Workspace layout (total ~3.5 MB):
//   dots : 25088 * 16 * 8 = 3,211,264 B @ 0
//   invn : 25088 * 8      =   200,704 B @ 3,211,264
//   wbf  : 64*9*64 * 2    =    73,728 B @ 3,411,968
// ---------------------------------------------------------------------------
extern "C" void kernel_launch(void* const* d_in, const int* in_sizes, int n_in,
                              void* d_out, int out_size, void* d_ws, size_t ws_size,
                              hipStream_t stream) {
    const float* x = (const float*)d_in[0];
    const float* w = (const float*)d_in[1];
    float* out = (float*)d_out;
    char* ws = (char*)d_ws;
    double*         dots = (double*)ws;
    double*         invn = (double*)(ws + 3211264);
    unsigned short* wbf  = (unsigned short*)(ws + 3411968);

    // 1470 blocks cover (b,r,s,j); 16 tail blocks pack wbf
    dots_kernel<<<1486, 256, 0, stream>>>(x, w, dots, invn, wbf);
    fused_kernel<<<dim3(2, 56, 8), 256, 0, stream>>>(x, dots, invn, wbf, out);
}

// Round 11
// 97.471 us; speedup vs baseline: 1.0621x; 1.0621x over previous
//
#include <hip/hip_runtime.h>
#include <hip/hip_bf16.h>
#include <float.h>

// Problem constants
#define BATCH 8
#define CHN   64
#define HW    56
#define PIX   3136          // 56*56
#define LDB   72            // band LDS stride in bf16 elems (144 B, 16-B aligned)
#define DSTR  16            // dots row stride (doubles): slots 0..14 used

typedef __bf16 bf16x8 __attribute__((ext_vector_type(8)));
typedef float  f32x4  __attribute__((ext_vector_type(4)));

static __device__ __forceinline__ unsigned short f2bf(float f) {
    unsigned int u = __float_as_uint(f);
    u += 0x7fffu + ((u >> 16) & 1u);          // round-to-nearest-even
    return (unsigned short)(u >> 16);
}

// ---------------------------------------------------------------------------
// Stage 1: dots[b][p][s], s=0..14 (window rows dr<=0), fp64 sequential over
// c=0..63 — bit-identical keys to the verified R1/R9 kernels. Rows dr=+1,+2
// are exact mirrors (IEEE mul commutes): read as dots[q][24-s] in stage 2.
// LDS-tiled (fixes R9's 192 MB center-column re-read -> ~24 MB):
// block = (b, r, half): stage rows r-2..r x 32 cols x 64 ch fp32 (24.6 KB),
// 512 threads; t<420 computes one (s, j) item: 64x(2 ds_read_b32 + f64 FMA).
// Same-row overlapping cols are same-address LDS broadcasts (free).
// s==12 (center) also emits invn. Blocks 896..911 pack wbf.
// ---------------------------------------------------------------------------
__global__ __launch_bounds__(512) void dots_kernel(const float* __restrict__ x,
                                                   const float* __restrict__ w,
                                                   double* __restrict__ dots,
                                                   double* __restrict__ invn,
                                                   unsigned short* __restrict__ wbf) {
    const int blk = blockIdx.x;
    const int t = threadIdx.x;
    if (blk >= 896) {                             // 16 tail blocks: pack wbf
        int wi = (blk - 896) * 512 + t;
        #pragma unroll
        for (int k = 0; k < 5; k++) {
            int l = wi + k * 8192;                // l = (o*9+tap)*64 + c
            if (l < 36864) {
                int otap = l >> 6, c = l & 63;
                int o = otap / 9, tap = otap - o * 9;
                wbf[l] = f2bf(w[(o * CHN + c) * 9 + tap]);
            }
        }
        return;
    }
    const int half = blk & 1;
    const int r = (blk >> 1) % HW;
    const int b = blk / 112;
    const int jbase = half * 28;

    __shared__ float tile[64 * 96];               // [ch][3 rows][32 cols] 24.6 KB
    // stage rows r-2..r, cols jbase-2..jbase+29 (zero-padded OOB)
    const float* xb = x + (size_t)b * CHN * PIX;
    for (int l = t; l < 6144; l += 512) {
        int c = l / 96, rem = l - c * 96;
        int lr = rem >> 5, lc = rem & 31;
        int row = r - 2 + lr;
        int col = jbase - 2 + lc;
        float v = 0.0f;
        if (row >= 0 && row < HW && col >= 0 && col < HW)
            v = xb[(size_t)c * PIX + row * HW + col];
        tile[l] = v;
    }
    __syncthreads();

    if (t >= 420) return;
    const int s = t / 28;                         // 0..14
    const int jl = t - s * 28;                    // local col 0..27
    const int j = jbase + jl;
    const int lr = s / 5;                         // source row offset (dr = lr-2)
    const int dc = s % 5 - 2;
    const float* ctr = &tile[2 * 32 + (jl + 2)];          // row r, col j
    const float* nbr = &tile[lr * 32 + (jl + dc + 2)];    // row r+lr-2, col j+dc

    double acc = 0.0;
    #pragma unroll 8
    for (int c = 0; c < CHN; c++) {
        acc += (double)ctr[c * 96] * (double)nbr[c * 96];
    }
    const int p = r * HW + j;
    dots[((size_t)b * PIX + p) * DSTR + s] = acc;
    if (s == 12) invn[(size_t)b * PIX + p] = 1.0 / sqrt(acc);
}

// ---------------------------------------------------------------------------
// Stage 2 (fused select + gather-conv), per (b, image row r).  [R9-verified,
// reverted from the R10 half-row split which duplicated per-block fixed
// costs]. Wave 0 (t<56): 25 keys from global dots (s<15 direct, s>=15
// mirror dots[q][24-s]) * invn[q], DBL_MAX invalid; 9-rank stable select +
// ascending index sort -> qtab. t in [56,64): zero qtab tail. t>=64: stage
// bf16 band from x. Then indexed-ds_read_b128 MFMA loop, direct out write.
// ---------------------------------------------------------------------------
__global__ __launch_bounds__(256) void fused_kernel(const float* __restrict__ x,
                                                    const double* __restrict__ dots,
                                                    const double* __restrict__ invn,
                                                    const unsigned short* __restrict__ wbf,
                                                    float* __restrict__ out) {
    const int b = blockIdx.y;
    const int r = blockIdx.x;
    __shared__ unsigned short band[300 * LDB];
    __shared__ int qtab[9 * 64];
    const int t = threadIdx.x;

    // A-fragments (registers; b128 loads from packed wbf)
    const int wv = t >> 6, ln = t & 63;
    const int mrow = ln & 15, kq = ln >> 4;
    const int o = wv * 16 + mrow;
    bf16x8 afr[9][2];
    #pragma unroll
    for (int tap = 0; tap < 9; tap++) {
        #pragma unroll
        for (int hf = 0; hf < 2; hf++) {
            afr[tap][hf] = *(const bf16x8*)(wbf + (size_t)(o * 9 + tap) * 64 + hf * 32 + kq * 8);
        }
    }

    if (t < 56) {
        const int jj = t;
        const double* dp  = dots + ((size_t)b * PIX + r * HW + jj) * DSTR;
        const double* inb = invn + (size_t)b * PIX;
        double k2[25];
        #pragma unroll
        for (int s = 0; s < 25; s++) {
            int dr = s / 5 - 2, dc = s % 5 - 2;
            int qi = r + dr, qj = jj + dc;
            bool valid = qi >= 0 && qi < HW && qj >= 0 && qj < HW;
            int q = qi * HW + qj;
            double raw;
            if (s < 15) raw = dp[s];
            else        raw = valid ? dots[((size_t)b * PIX + q) * DSTR + (24 - s)] : 0.0;
            k2[s] = valid ? raw * inb[q] : DBL_MAX;
        }
        unsigned int used = 0;
        int bq[9];
        #pragma unroll
        for (int rr = 0; rr < 9; rr++) {
            double best = DBL_MAX; int bs = 0;
            #pragma unroll
            for (int s = 0; s < 25; s++) {
                bool ok = (((used >> s) & 1u) == 0u) && (k2[s] < best);
                if (ok) { best = k2[s]; bs = s; }
            }
            used |= (1u << bs);
            bq[rr] = (r + bs / 5 - 2) * HW + (jj + bs % 5 - 2);
        }
        #pragma unroll
        for (int a = 0; a < 8; a++) {
            #pragma unroll
            for (int c2 = 0; c2 < 8 - a; c2++) {
                int u = bq[c2], v = bq[c2 + 1];
                bq[c2] = u < v ? u : v; bq[c2 + 1] = u < v ? v : u;
            }
        }
        #pragma unroll
        for (int k = 0; k < 9; k++) {
            int q = bq[k], qi = q / HW, qj = q - qi * HW;
            qtab[k * 64 + jj] = ((qi - r + 2) * 60 + qj + 2) * LDB;
        }
    } else if (t < 64) {
        #pragma unroll
        for (int k = 0; k < 9; k++) qtab[k * 64 + t] = 0;   // tail dummy
    } else {
        // band: 300 locals x 32 channel-pairs; lanes sweep locals (coalesced)
        const float* xb = x + (size_t)b * CHN * PIX;
        for (int l = t - 64; l < 9600; l += 192) {
            int cpair = l / 300;
            int local = l - cpair * 300;
            int lr = local / 60, col = local - lr * 60 - 2;
            int row = r - 2 + lr;
            unsigned int pk = 0;
            if (row >= 0 && row < HW && col >= 0 && col < HW) {
                int q = row * HW + col;
                float v0 = xb[(size_t)(2 * cpair) * PIX + q];
                float v1 = xb[(size_t)(2 * cpair + 1) * PIX + q];
                pk = (unsigned int)f2bf(v0) | ((unsigned int)f2bf(v1) << 16);
            }
            *(unsigned int*)&band[local * LDB + 2 * cpair] = pk;
        }
    }
    __syncthreads();

    // MFMA gather-conv (verified R5/R8/R9)
    f32x4 oacc[4] = {{0,0,0,0},{0,0,0,0},{0,0,0,0},{0,0,0,0}};
    #pragma unroll
    for (int tap = 0; tap < 9; tap++) {
        #pragma unroll
        for (int nt = 0; nt < 4; nt++) {
            int q = qtab[tap * 64 + nt * 16 + mrow];
            const unsigned short* bp = &band[q + kq * 8];
            bf16x8 b0 = *(const bf16x8*)bp;
            bf16x8 b1 = *(const bf16x8*)(bp + 32);
            oacc[nt] = __builtin_amdgcn_mfma_f32_16x16x32_bf16(afr[tap][0], b0, oacc[nt], 0, 0, 0);
            oacc[nt] = __builtin_amdgcn_mfma_f32_16x16x32_bf16(afr[tap][1], b1, oacc[nt], 0, 0, 0);
        }
    }
    // C/D: col = lane&15 = p-within-tile, row = kq*4+rg = o-within-strip
    float* ob = out + ((size_t)b * 64 + wv * 16 + kq * 4) * PIX + r * HW;
    #pragma unroll
    for (int nt = 0; nt < 4; nt++) {
        int p = nt * 16 + mrow;
        if (p < HW) {
            #pragma unroll
            for (int rg = 0; rg < 4; rg++) ob[(size_t)rg * PIX + p] = oacc[nt][rg];
        }
    }
}

// ---------------------------------------------------------------------------
// Workspace layout (total ~3.5 MB):
//   dots : 25088 * 16 * 8 = 3,211,264 B @ 0
//   invn : 25088 * 8      =   200,704 B @ 3,211,264
//   wbf  : 64*9*64 * 2    =    73,728 B @ 3,411,968
// ---------------------------------------------------------------------------
extern "C" void kernel_launch(void* const* d_in, const int* in_sizes, int n_in,
                              void* d_out, int out_size, void* d_ws, size_t ws_size,
                              hipStream_t stream) {
    const float* x = (const float*)d_in[0];
    const float* w = (const float*)d_in[1];
    float* out = (float*)d_out;
    char* ws = (char*)d_ws;
    double*         dots = (double*)ws;
    double*         invn = (double*)(ws + 3211264);
    unsigned short* wbf  = (unsigned short*)(ws + 3411968);

    // 896 blocks cover (b,r,half); 16 tail blocks pack wbf
    dots_kernel<<<912, 512, 0, stream>>>(x, w, dots, invn, wbf);
    fused_kernel<<<dim3(56, 8), 256, 0, stream>>>(x, dots, invn, wbf, out);
}

// Round 12
// 90.193 us; speedup vs baseline: 1.1478x; 1.0807x over previous
//
#include <hip/hip_runtime.h>
#include <hip/hip_bf16.h>
#include <float.h>

// Problem constants
#define BATCH 8
#define CHN   64
#define HW    56
#define PIX   3136          // 56*56
#define LDB   72            // band LDS stride in bf16 elems (144 B, 16-B aligned)
#define DSTR  16            // dots row stride (doubles): slots 0..12 used
#define TS    66            // dots tile stride in floats (2-way bank alias = free)

typedef __bf16 bf16x8 __attribute__((ext_vector_type(8)));
typedef float  f32x4  __attribute__((ext_vector_type(4)));

static __device__ __forceinline__ unsigned short f2bf(float f) {
    unsigned int u = __float_as_uint(f);
    u += 0x7fffu + ((u >> 16) & 1u);          // round-to-nearest-even
    return (unsigned short)(u >> 16);
}

// ---------------------------------------------------------------------------
// Stage 1: dots[b][p][s], s=0..12 (13 slots; 13/14 are row-internal mirrors
// handled by fused's 24-s read; rows dr=+1,+2 likewise). fp64 sequential
// over c=0..63 — bit-identical keys to the verified R1/R9 kernels.
// Block = (b, r, half): tile[local=lr*32+lc][c] f32, stride TS=66 (25.3 KB;
// consecutive-local accesses are +66 dw = 2-way bank alias = free, and b64
// c-pair reads stay 8-B aligned). Compute threads t<364 = (s,jl): 32 x
// (2 ds_read_b64 + 2 f64 FMA). Threads also emit bf16 xT for row r (read
// tile c-contiguous, pack, uint2 store) — feeds fused's uint4 staging.
// s==12 (center) also emits invn. Blocks 896..911 pack wbf.
// ---------------------------------------------------------------------------
__global__ __launch_bounds__(512) void dots_kernel(const float* __restrict__ x,
                                                   const float* __restrict__ w,
                                                   double* __restrict__ dots,
                                                   double* __restrict__ invn,
                                                   unsigned short* __restrict__ wbf,
                                                   unsigned short* __restrict__ xT) {
    const int blk = blockIdx.x;
    const int t = threadIdx.x;
    if (blk >= 896) {                             // 16 tail blocks: pack wbf
        int wi = (blk - 896) * 512 + t;
        #pragma unroll
        for (int k = 0; k < 5; k++) {
            int l = wi + k * 8192;                // l = (o*9+tap)*64 + c
            if (l < 36864) {
                int otap = l >> 6, c = l & 63;
                int o = otap / 9, tap = otap - o * 9;
                wbf[l] = f2bf(w[(o * CHN + c) * 9 + tap]);
            }
        }
        return;
    }
    const int half = blk & 1;
    const int r = (blk >> 1) % HW;
    const int b = blk / 112;
    const int jbase = half * 28;

    __shared__ float tile[96 * TS];               // [3 rows x 32 cols][64 ch]
    // stage rows r-2..r, cols jbase-2..jbase+29 (zero-padded OOB).
    // Global reads coalesced in col; LDS writes +TS dw apart = 2-way (free).
    const float* xb = x + (size_t)b * CHN * PIX;
    for (int l = t; l < 6144; l += 512) {
        int c = l / 96, rem = l - c * 96;
        int lr = rem >> 5, lc = rem & 31;
        int row = r - 2 + lr;
        int col = jbase - 2 + lc;
        float v = 0.0f;
        if (row >= 0 && row < HW && col >= 0 && col < HW)
            v = xb[(size_t)c * PIX + row * HW + col];
        tile[(lr * 32 + lc) * TS + c] = v;
    }
    __syncthreads();

    // xT emit: t<448: jl = t>>4 (0..27), oct = t&15 -> 4 channels
    if (t < 448) {
        const int jl = t >> 4, oct = t & 15;
        const float* src = &tile[(66 + jl) * TS + oct * 4];   // ctr row local = 66+jl
        float2 f0 = *(const float2*)(src);
        float2 f1 = *(const float2*)(src + 2);
        uint2 pk;
        pk.x = (unsigned int)f2bf(f0.x) | ((unsigned int)f2bf(f0.y) << 16);
        pk.y = (unsigned int)f2bf(f1.x) | ((unsigned int)f2bf(f1.y) << 16);
        *(uint2*)(xT + ((size_t)b * PIX + r * HW + jbase + jl) * CHN + oct * 4) = pk;
    }

    if (t >= 364) return;
    const int s = t / 28;                         // 0..12
    const int jl = t - s * 28;                    // local col 0..27
    const int lr = s / 5;                         // dr = lr-2 in {-2,-1,0}
    const int dc = s % 5 - 2;
    const float* ctr = &tile[(66 + jl) * TS];             // row r, col jbase+jl
    const float* nbr = &tile[(lr * 32 + jl + dc + 2) * TS];

    double acc = 0.0;
    #pragma unroll 8
    for (int k = 0; k < 32; k++) {
        float2 cv = *(const float2*)(ctr + 2 * k);
        float2 nv = *(const float2*)(nbr + 2 * k);
        acc += (double)cv.x * (double)nv.x;       // c = 2k
        acc += (double)cv.y * (double)nv.y;       // c = 2k+1 (sequential order kept)
    }
    const int p = r * HW + jbase + jl;
    dots[((size_t)b * PIX + p) * DSTR + s] = acc;
    if (s == 12) invn[(size_t)b * PIX + p] = 1.0 / sqrt(acc);
}

// ---------------------------------------------------------------------------
// Stage 2 (fused select + gather-conv), per (b, image row r).
// Wave 0 (t<56): 25 keys — s<13 direct, s>=13 mirror dots[q][24-s] (exact:
// IEEE mul commutes) * invn[q], DBL_MAX invalid; 9-rank stable select +
// ascending index sort -> qtab. t in [56,64): zero qtab tail. t>=64: stage
// bf16 band from xT via uint4 (R5-proven coalesced staging). Then
// indexed-ds_read_b128 MFMA loop, direct out write.
// ---------------------------------------------------------------------------
__global__ __launch_bounds__(256) void fused_kernel(const unsigned short* __restrict__ xT,
                                                    const double* __restrict__ dots,
                                                    const double* __restrict__ invn,
                                                    const unsigned short* __restrict__ wbf,
                                                    float* __restrict__ out) {
    const int b = blockIdx.y;
    const int r = blockIdx.x;
    __shared__ unsigned short band[300 * LDB];
    __shared__ int qtab[9 * 64];
    const int t = threadIdx.x;

    // A-fragments (registers; b128 loads from packed wbf)
    const int wv = t >> 6, ln = t & 63;
    const int mrow = ln & 15, kq = ln >> 4;
    const int o = wv * 16 + mrow;
    bf16x8 afr[9][2];
    #pragma unroll
    for (int tap = 0; tap < 9; tap++) {
        #pragma unroll
        for (int hf = 0; hf < 2; hf++) {
            afr[tap][hf] = *(const bf16x8*)(wbf + (size_t)(o * 9 + tap) * 64 + hf * 32 + kq * 8);
        }
    }

    if (t < 56) {
        const int jj = t;
        const double* dp  = dots + ((size_t)b * PIX + r * HW + jj) * DSTR;
        const double* inb = invn + (size_t)b * PIX;
        double k2[25];
        #pragma unroll
        for (int s = 0; s < 25; s++) {
            int dr = s / 5 - 2, dc = s % 5 - 2;
            int qi = r + dr, qj = jj + dc;
            bool valid = qi >= 0 && qi < HW && qj >= 0 && qj < HW;
            int q = qi * HW + qj;
            double raw;
            if (s < 13) raw = dp[s];
            else        raw = valid ? dots[((size_t)b * PIX + q) * DSTR + (24 - s)] : 0.0;
            k2[s] = valid ? raw * inb[q] : DBL_MAX;
        }
        unsigned int used = 0;
        int bq[9];
        #pragma unroll
        for (int rr = 0; rr < 9; rr++) {
            double best = DBL_MAX; int bs = 0;
            #pragma unroll
            for (int s = 0; s < 25; s++) {
                bool ok = (((used >> s) & 1u) == 0u) && (k2[s] < best);
                if (ok) { best = k2[s]; bs = s; }
            }
            used |= (1u << bs);
            bq[rr] = (r + bs / 5 - 2) * HW + (jj + bs % 5 - 2);
        }
        #pragma unroll
        for (int a = 0; a < 8; a++) {
            #pragma unroll
            for (int c2 = 0; c2 < 8 - a; c2++) {
                int u = bq[c2], v = bq[c2 + 1];
                bq[c2] = u < v ? u : v; bq[c2 + 1] = u < v ? v : u;
            }
        }
        #pragma unroll
        for (int k = 0; k < 9; k++) {
            int q = bq[k], qi = q / HW, qj = q - qi * HW;
            qtab[k * 64 + jj] = ((qi - r + 2) * 60 + qj + 2) * LDB;
        }
    } else if (t < 64) {
        #pragma unroll
        for (int k = 0; k < 9; k++) qtab[k * 64 + t] = 0;   // tail dummy
    } else {
        // band: 300 locals x 8 ch-octs, uint4 both sides (R5-proven)
        for (int l = t - 64; l < 2400; l += 192) {
            int local = l >> 3, ch8 = l & 7;
            int lr = local / 60, col = local - lr * 60 - 2;
            int row = r - 2 + lr;
            uint4 v = {0, 0, 0, 0};
            if (row >= 0 && row < HW && col >= 0 && col < HW)
                v = *(const uint4*)(xT + ((size_t)b * PIX + row * HW + col) * CHN + ch8 * 8);
            *(uint4*)(&band[local * LDB + ch8 * 8]) = v;
        }
    }
    __syncthreads();

    // MFMA gather-conv (verified R5/R8/R9)
    f32x4 oacc[4] = {{0,0,0,0},{0,0,0,0},{0,0,0,0},{0,0,0,0}};
    #pragma unroll
    for (int tap = 0; tap < 9; tap++) {
        #pragma unroll
        for (int nt = 0; nt < 4; nt++) {
            int q = qtab[tap * 64 + nt * 16 + mrow];
            const unsigned short* bp = &band[q + kq * 8];
            bf16x8 b0 = *(const bf16x8*)bp;
            bf16x8 b1 = *(const bf16x8*)(bp + 32);
            oacc[nt] = __builtin_amdgcn_mfma_f32_16x16x32_bf16(afr[tap][0], b0, oacc[nt], 0, 0, 0);
            oacc[nt] = __builtin_amdgcn_mfma_f32_16x16x32_bf16(afr[tap][1], b1, oacc[nt], 0, 0, 0);
        }
    }
    // C/D: col = lane&15 = p-within-tile, row = kq*4+rg = o-within-strip
    float* ob = out + ((size_t)b * 64 + wv * 16 + kq * 4) * PIX + r * HW;
    #pragma unroll
    for (int nt = 0; nt < 4; nt++) {
        int p = nt * 16 + mrow;
        if (p < HW) {
            #pragma unroll
            for (int rg = 0; rg < 4; rg++) ob[(size_t)rg * PIX + p] = oacc[nt][rg];
        }
    }
}

// ---------------------------------------------------------------------------
// Workspace layout (total ~6.7 MB):
//   dots : 25088 * 16 * 8 = 3,211,264 B @ 0
//   invn : 25088 * 8      =   200,704 B @ 3,211,264
//   wbf  : 64*9*64 * 2    =    73,728 B @ 3,411,968
//   xT   : 8*3136*64 * 2  = 3,211,264 B @ 3,485,696
// ---------------------------------------------------------------------------
extern "C" void kernel_launch(void* const* d_in, const int* in_sizes, int n_in,
                              void* d_out, int out_size, void* d_ws, size_t ws_size,
                              hipStream_t stream) {
    const float* x = (const float*)d_in[0];
    const float* w = (const float*)d_in[1];
    float* out = (float*)d_out;
    char* ws = (char*)d_ws;
    double*         dots = (double*)ws;
    double*         invn = (double*)(ws + 3211264);
    unsigned short* wbf  = (unsigned short*)(ws + 3411968);
    unsigned short* xT   = (unsigned short*)(ws + 3485696);

    // 896 blocks cover (b,r,half); 16 tail blocks pack wbf
    dots_kernel<<<912, 512, 0, stream>>>(x, w, dots, invn, wbf, xT);
    fused_kernel<<<dim3(56, 8), 256, 0, stream>>>(xT, dots, invn, wbf, out);
}

// Round 13
// 90.145 us; speedup vs baseline: 1.1484x; 1.0005x over previous
//
#include <hip/hip_runtime.h>
#include <hip/hip_bf16.h>
#include <float.h>

// Problem constants
#define BATCH 8
#define CHN   64
#define HW    56
#define PIX   3136          // 56*56
#define LDB   72            // band LDS stride in bf16 elems (144 B, 16-B aligned)
#define DSTR  16            // dots row stride (doubles): slots 0..12 used
#define TS    66            // dots tile stride in floats (2-way bank alias = free)
#define QW    14            // pixels per dots block (quarter row)
#define QC    18            // tile cols (QW + 4 halo)
#define NLOC  54            // 3 rows x 18 cols

typedef __bf16 bf16x8 __attribute__((ext_vector_type(8)));
typedef float  f32x4  __attribute__((ext_vector_type(4)));

static __device__ __forceinline__ unsigned short f2bf(float f) {
    unsigned int u = __float_as_uint(f);
    u += 0x7fffu + ((u >> 16) & 1u);          // round-to-nearest-even
    return (unsigned short)(u >> 16);
}

// ---------------------------------------------------------------------------
// Stage 1: dots[b][p][s], s=0..12 (13 unique slots; 13/14 + rows dr>0 are
// exact mirrors read as dots[q][24-s] downstream). fp64 sequential over
// c=0..63 — bit-identical keys to the verified R1/R9/R12 kernels.
// R13: quarter-row blocks (256 thr, tile 14.3 KB) -> 8 co-resident blocks/CU
// (R12 had 3.5 at 512 thr/25.3 KB) to bury staging latency + barrier drain
// under neighbor-block compute. Per-wave issue mix identical to R12:
// 32 b64-pair reads x2 + 128 cvt + 64 f64 FMA.
// Layout: tile[local=lr*QC+lc][c], stride TS=66 (2-way bank alias = free).
// t<182 = (s,jl) computes one slot; t<224 emits bf16 xT (uint2, 4 ch);
// s==12 emits invn. Blocks 1792..1807 pack wbf.
// ---------------------------------------------------------------------------
__global__ __launch_bounds__(256) void dots_kernel(const float* __restrict__ x,
                                                   const float* __restrict__ w,
                                                   double* __restrict__ dots,
                                                   double* __restrict__ invn,
                                                   unsigned short* __restrict__ wbf,
                                                   unsigned short* __restrict__ xT) {
    const int blk = blockIdx.x;
    const int t = threadIdx.x;
    if (blk >= 1792) {                            // 16 tail blocks: pack wbf
        int wi = (blk - 1792) * 256 + t;          // 0..4095
        #pragma unroll
        for (int k = 0; k < 9; k++) {
            int l = wi + k * 4096;                // l = (o*9+tap)*64 + c
            int otap = l >> 6, c = l & 63;
            int o = otap / 9, tap = otap - o * 9;
            wbf[l] = f2bf(w[(o * CHN + c) * 9 + tap]);
        }
        return;
    }
    const int quarter = blk & 3;
    const int r = (blk >> 2) % HW;
    const int b = blk / 224;
    const int jbase = quarter * QW;

    __shared__ float tile[NLOC * TS];             // 14.3 KB
    // stage rows r-2..r, cols jbase-2..jbase+15 (zero-padded OOB)
    const float* xb = x + (size_t)b * CHN * PIX;
    for (int l = t; l < NLOC * CHN; l += 256) {
        int c = l / NLOC, rem = l - c * NLOC;
        int lr = rem / QC, lc = rem - lr * QC;
        int row = r - 2 + lr;
        int col = jbase - 2 + lc;
        float v = 0.0f;
        if (row >= 0 && row < HW && col >= 0 && col < HW)
            v = xb[(size_t)c * PIX + row * HW + col];
        tile[rem * TS + c] = v;
    }
    __syncthreads();

    // xT emit: t<224: jl = t>>4 (0..13), oct = t&15 -> 4 channels
    if (t < 224) {
        const int jl = t >> 4, oct = t & 15;
        const float* src = &tile[(2 * QC + 2 + jl) * TS + oct * 4];
        float2 f0 = *(const float2*)(src);
        float2 f1 = *(const float2*)(src + 2);
        uint2 pk;
        pk.x = (unsigned int)f2bf(f0.x) | ((unsigned int)f2bf(f0.y) << 16);
        pk.y = (unsigned int)f2bf(f1.x) | ((unsigned int)f2bf(f1.y) << 16);
        *(uint2*)(xT + ((size_t)b * PIX + r * HW + jbase + jl) * CHN + oct * 4) = pk;
    }

    if (t >= 182) return;
    const int s = t / QW;                         // 0..12
    const int jl = t - s * QW;                    // local col 0..13
    const int lr = s / 5;                         // dr = lr-2 in {-2,-1,0}
    const int dc = s % 5 - 2;
    const float* ctr = &tile[(2 * QC + 2 + jl) * TS];
    const float* nbr = &tile[(lr * QC + jl + dc + 2) * TS];

    double acc = 0.0;
    #pragma unroll 8
    for (int k = 0; k < 32; k++) {
        float2 cv = *(const float2*)(ctr + 2 * k);
        float2 nv = *(const float2*)(nbr + 2 * k);
        acc += (double)cv.x * (double)nv.x;       // c = 2k
        acc += (double)cv.y * (double)nv.y;       // c = 2k+1 (sequential order kept)
    }
    const int p = r * HW + jbase + jl;
    dots[((size_t)b * PIX + p) * DSTR + s] = acc;
    if (s == 12) invn[(size_t)b * PIX + p] = 1.0 / sqrt(acc);
}

// ---------------------------------------------------------------------------
// Stage 2 (fused select + gather-conv), per (b, image row r).  [R12-verified]
// Wave 0 (t<56): 25 keys — s<13 direct, s>=13 mirror dots[q][24-s] (exact:
// IEEE mul commutes) * invn[q], DBL_MAX invalid; 9-rank stable select +
// ascending index sort -> qtab. t in [56,64): zero qtab tail. t>=64: stage
// bf16 band from xT via uint4. Then indexed-ds_read_b128 MFMA, direct out.
// ---------------------------------------------------------------------------
__global__ __launch_bounds__(256) void fused_kernel(const unsigned short* __restrict__ xT,
                                                    const double* __restrict__ dots,
                                                    const double* __restrict__ invn,
                                                    const unsigned short* __restrict__ wbf,
                                                    float* __restrict__ out) {
    const int b = blockIdx.y;
    const int r = blockIdx.x;
    __shared__ unsigned short band[300 * LDB];
    __shared__ int qtab[9 * 64];
    const int t = threadIdx.x;

    // A-fragments (registers; b128 loads from packed wbf)
    const int wv = t >> 6, ln = t & 63;
    const int mrow = ln & 15, kq = ln >> 4;
    const int o = wv * 16 + mrow;
    bf16x8 afr[9][2];
    #pragma unroll
    for (int tap = 0; tap < 9; tap++) {
        #pragma unroll
        for (int hf = 0; hf < 2; hf++) {
            afr[tap][hf] = *(const bf16x8*)(wbf + (size_t)(o * 9 + tap) * 64 + hf * 32 + kq * 8);
        }
    }

    if (t < 56) {
        const int jj = t;
        const double* dp  = dots + ((size_t)b * PIX + r * HW + jj) * DSTR;
        const double* inb = invn + (size_t)b * PIX;
        double k2[25];
        #pragma unroll
        for (int s = 0; s < 25; s++) {
            int dr = s / 5 - 2, dc = s % 5 - 2;
            int qi = r + dr, qj = jj + dc;
            bool valid = qi >= 0 && qi < HW && qj >= 0 && qj < HW;
            int q = qi * HW + qj;
            double raw;
            if (s < 13) raw = dp[s];
            else        raw = valid ? dots[((size_t)b * PIX + q) * DSTR + (24 - s)] : 0.0;
            k2[s] = valid ? raw * inb[q] : DBL_MAX;
        }
        unsigned int used = 0;
        int bq[9];
        #pragma unroll
        for (int rr = 0; rr < 9; rr++) {
            double best = DBL_MAX; int bs = 0;
            #pragma unroll
            for (int s = 0; s < 25; s++) {
                bool ok = (((used >> s) & 1u) == 0u) && (k2[s] < best);
                if (ok) { best = k2[s]; bs = s; }
            }
            used |= (1u << bs);
            bq[rr] = (r + bs / 5 - 2) * HW + (jj + bs % 5 - 2);
        }
        #pragma unroll
        for (int a = 0; a < 8; a++) {
            #pragma unroll
            for (int c2 = 0; c2 < 8 - a; c2++) {
                int u = bq[c2], v = bq[c2 + 1];
                bq[c2] = u < v ? u : v; bq[c2 + 1] = u < v ? v : u;
            }
        }
        #pragma unroll
        for (int k = 0; k < 9; k++) {
            int q = bq[k], qi = q / HW, qj = q - qi * HW;
            qtab[k * 64 + jj] = ((qi - r + 2) * 60 + qj + 2) * LDB;
        }
    } else if (t < 64) {
        #pragma unroll
        for (int k = 0; k < 9; k++) qtab[k * 64 + t] = 0;   // tail dummy
    } else {
        // band: 300 locals x 8 ch-octs, uint4 both sides
        for (int l = t - 64; l < 2400; l += 192) {
            int local = l >> 3, ch8 = l & 7;
            int lr = local / 60, col = local - lr * 60 - 2;
            int row = r - 2 + lr;
            uint4 v = {0, 0, 0, 0};
            if (row >= 0 && row < HW && col >= 0 && col < HW)
                v = *(const uint4*)(xT + ((size_t)b * PIX + row * HW + col) * CHN + ch8 * 8);
            *(uint4*)(&band[local * LDB + ch8 * 8]) = v;
        }
    }
    __syncthreads();

    // MFMA gather-conv (verified R5/R8/R9/R12)
    f32x4 oacc[4] = {{0,0,0,0},{0,0,0,0},{0,0,0,0},{0,0,0,0}};
    #pragma unroll
    for (int tap = 0; tap < 9; tap++) {
        #pragma unroll
        for (int nt = 0; nt < 4; nt++) {
            int q = qtab[tap * 64 + nt * 16 + mrow];
            const unsigned short* bp = &band[q + kq * 8];
            bf16x8 b0 = *(const bf16x8*)bp;
            bf16x8 b1 = *(const bf16x8*)(bp + 32);
            oacc[nt] = __builtin_amdgcn_mfma_f32_16x16x32_bf16(afr[tap][0], b0, oacc[nt], 0, 0, 0);
            oacc[nt] = __builtin_amdgcn_mfma_f32_16x16x32_bf16(afr[tap][1], b1, oacc[nt], 0, 0, 0);
        }
    }
    // C/D: col = lane&15 = p-within-tile, row = kq*4+rg = o-within-strip
    float* ob = out + ((size_t)b * 64 + wv * 16 + kq * 4) * PIX + r * HW;
    #pragma unroll
    for (int nt = 0; nt < 4; nt++) {
        int p = nt * 16 + mrow;
        if (p < HW) {
            #pragma unroll
            for (int rg = 0; rg < 4; rg++) ob[(size_t)rg * PIX + p] = oacc[nt][rg];
        }
    }
}

// ---------------------------------------------------------------------------
// Workspace layout (total ~6.7 MB):
//   dots : 25088 * 16 * 8 = 3,211,264 B @ 0
//   invn : 25088 * 8      =   200,704 B @ 3,211,264
//   wbf  : 64*9*64 * 2    =    73,728 B @ 3,411,968
//   xT   : 8*3136*64 * 2  = 3,211,264 B @ 3,485,696
// ---------------------------------------------------------------------------
extern "C" void kernel_launch(void* const* d_in, const int* in_sizes, int n_in,
                              void* d_out, int out_size, void* d_ws, size_t ws_size,
                              hipStream_t stream) {
    const float* x = (const float*)d_in[0];
    const float* w = (const float*)d_in[1];
    float* out = (float*)d_out;
    char* ws = (char*)d_ws;
    double*         dots = (double*)ws;
    double*         invn = (double*)(ws + 3211264);
    unsigned short* wbf  = (unsigned short*)(ws + 3411968);
    unsigned short* xT   = (unsigned short*)(ws + 3485696);

    // 1792 blocks cover (b,r,quarter); 16 tail blocks pack wbf
    dots_kernel<<<1808, 256, 0, stream>>>(x, w, dots, invn, wbf, xT);
    fused_kernel<<<dim3(56, 8), 256, 0, stream>>>(xT, dots, invn, wbf, out);
}